// Round 3
// baseline (390.216 us; speedup 1.0000x reference)
//
#include <hip/hip_runtime.h>
#include <hip/hip_bf16.h>

#define SCLOG (0.125f * 1.4426950408889634f)

typedef __attribute__((ext_vector_type(8))) short short8;
typedef __attribute__((ext_vector_type(4))) short s16x4;
typedef __attribute__((ext_vector_type(4))) float f32x4;

__device__ __forceinline__ short f2bf(float f) {
    __hip_bfloat16 h = __float2bfloat16(f);
    short s;
    __builtin_memcpy(&s, &h, 2);
    return s;
}

// async global->LDS, 16B/lane; LDS dest = wave-uniform base + lane*16.
__device__ __forceinline__ void gl_lds16(const void* g, void* l) {
    __builtin_amdgcn_global_load_lds(
        (const __attribute__((address_space(1))) unsigned int*)g,
        (__attribute__((address_space(3))) unsigned int*)l,
        16, 0, 0);
}

// fp32 -> bf16 elementwise, 8 elems/thread, arrays selected by blockIdx.y
__global__ __launch_bounds__(256) void cvt3(
    const float* __restrict__ a, const float* __restrict__ b,
    const float* __restrict__ c, short* __restrict__ oa,
    short* __restrict__ ob, short* __restrict__ oc, int n8)
{
    int i = blockIdx.x * 256 + threadIdx.x;
    if (i >= n8) return;
    const float* in = blockIdx.y == 0 ? a : (blockIdx.y == 1 ? b : c);
    short* out = blockIdx.y == 0 ? oa : (blockIdx.y == 1 ? ob : oc);
    float4 v0 = ((const float4*)in)[2 * i];
    float4 v1 = ((const float4*)in)[2 * i + 1];
    short8 s = { f2bf(v0.x), f2bf(v0.y), f2bf(v0.z), f2bf(v0.w),
                 f2bf(v1.x), f2bf(v1.y), f2bf(v1.z), f2bf(v1.w) };
    *(short8*)(out + 8 * (size_t)i) = s;
}

__global__ __launch_bounds__(256) void cvt4(
    const float* __restrict__ a, const float* __restrict__ b,
    const float* __restrict__ c, const float* __restrict__ d,
    short* __restrict__ oa, short* __restrict__ ob,
    short* __restrict__ oc, short* __restrict__ od, int n8)
{
    int i = blockIdx.x * 256 + threadIdx.x;
    if (i >= n8) return;
    const float* in = blockIdx.y == 0 ? a : (blockIdx.y == 1 ? b :
                      (blockIdx.y == 2 ? c : d));
    short* out = blockIdx.y == 0 ? oa : (blockIdx.y == 1 ? ob :
                 (blockIdx.y == 2 ? oc : od));
    float4 v0 = ((const float4*)in)[2 * i];
    float4 v1 = ((const float4*)in)[2 * i + 1];
    short8 s = { f2bf(v0.x), f2bf(v0.y), f2bf(v0.z), f2bf(v0.w),
                 f2bf(v1.x), f2bf(v1.y), f2bf(v1.z), f2bf(v1.w) };
    *(short8*)(out + 8 * (size_t)i) = s;
}

// C[M,N] = A[M,K] @ W[N,K]^T + bias, bf16 in. 128x128 tile, BK=64,
// global_load_lds staging with XOR chunk swizzle. QKV fused via blockIdx.z.
// VTOUT: for z==2 write C transposed as VT[b,h,d,s] (fuses transpose_v).
template<int NZ, bool OUT_BF16, bool VTOUT>
__global__ __launch_bounds__(256) void gemm_bt_bf16(
    const short* __restrict__ A0, const short* __restrict__ A1,
    const short* __restrict__ A2,
    const short* __restrict__ W0, const short* __restrict__ W1,
    const short* __restrict__ W2,
    const float* __restrict__ b0, const float* __restrict__ b1,
    const float* __restrict__ b2,
    short* __restrict__ C0, short* __restrict__ C1, short* __restrict__ C2,
    void* __restrict__ Cf, int M, int N, int K)
{
    __shared__ short As[128 * 64];
    __shared__ short Bs[128 * 64];
    const int tid = threadIdx.x;
    const int wave = tid >> 6, lane = tid & 63;
    const int quad = lane >> 4, l16 = lane & 15;
    const int wm = (wave >> 1) * 64, wn = (wave & 1) * 64;
    const int bm0 = blockIdx.y * 128, bn0 = blockIdx.x * 128;
    const int rowA = lane >> 3;
    const int chunkS = (((lane & 7) ^ rowA) * 8);   // swizzled global chunk
    const int rsw = (l16 & 7);                      // read-side row swizzle key

    const short* A; const short* W; const float* bias; short* Cb;
    if constexpr (NZ == 3) {
        A    = blockIdx.z == 0 ? A0 : (blockIdx.z == 1 ? A1 : A2);
        W    = blockIdx.z == 0 ? W0 : (blockIdx.z == 1 ? W1 : W2);
        bias = blockIdx.z == 0 ? b0 : (blockIdx.z == 1 ? b1 : b2);
        Cb   = blockIdx.z == 0 ? C0 : (blockIdx.z == 1 ? C1 : C2);
    } else {
        A = A0; W = W0; bias = b0; Cb = C0;
    }

    const short* Ab = A + (size_t)bm0 * K;
    const short* Wb = W + (size_t)bn0 * K;

    f32x4 acc[4][4] = {};

    for (int kt = 0; kt < K; kt += 64) {
        #pragma unroll
        for (int i = 0; i < 4; ++i) {
            int r0 = wave * 32 + i * 8;
            gl_lds16(Ab + (size_t)(r0 + rowA) * K + kt + chunkS, As + r0 * 64);
            gl_lds16(Wb + (size_t)(r0 + rowA) * K + kt + chunkS, Bs + r0 * 64);
        }
        __syncthreads();

        #pragma unroll
        for (int h = 0; h < 2; ++h) {
            const int slot = ((h * 4 + quad) ^ rsw) * 8;
            short8 af[4], bf[4];
            #pragma unroll
            for (int mi = 0; mi < 4; ++mi)
                af[mi] = *(const short8*)(As + (wm + mi * 16 + l16) * 64 + slot);
            #pragma unroll
            for (int ni = 0; ni < 4; ++ni)
                bf[ni] = *(const short8*)(Bs + (wn + ni * 16 + l16) * 64 + slot);
            #pragma unroll
            for (int mi = 0; mi < 4; ++mi)
                #pragma unroll
                for (int ni = 0; ni < 4; ++ni)
                    acc[mi][ni] = __builtin_amdgcn_mfma_f32_16x16x32_bf16(
                        af[mi], bf[ni], acc[mi][ni], 0, 0, 0);
        }
        __syncthreads();
    }

    // epilogue: C/D layout col=lane&15 (N), row=quad*4+reg (M)
    bool vt_mode = false;
    if constexpr (VTOUT) vt_mode = (blockIdx.z == 2);

    if (vt_mode) {
        // write VT[b, h=n>>6, d=n&63, s=m&2047]; 4 r-values are s-contiguous
        const int SS = 2048;
        const int bidx = bm0 >> 11;         // 128-row tile never crosses b
        const int s0b  = (bm0 & 2047) + wm;
        #pragma unroll
        for (int ni = 0; ni < 4; ++ni) {
            int n = bn0 + wn + ni * 16 + l16;
            float bb = bias[n];
            int hh = n >> 6, dd = n & 63;
            short* vrow = Cb + ((size_t)((bidx * 16 + hh) * 64 + dd)) * SS;
            #pragma unroll
            for (int mi = 0; mi < 4; ++mi) {
                int s0 = s0b + mi * 16 + quad * 4;
                s16x4 pk = { f2bf(acc[mi][ni][0] + bb), f2bf(acc[mi][ni][1] + bb),
                             f2bf(acc[mi][ni][2] + bb), f2bf(acc[mi][ni][3] + bb) };
                *(s16x4*)(vrow + s0) = pk;
            }
        }
    } else {
        #pragma unroll
        for (int ni = 0; ni < 4; ++ni) {
            int n = bn0 + wn + ni * 16 + l16;
            float bb = bias[n];
            #pragma unroll
            for (int mi = 0; mi < 4; ++mi)
                #pragma unroll
                for (int r = 0; r < 4; ++r) {
                    int m = bm0 + wm + mi * 16 + quad * 4 + r;
                    float v = acc[mi][ni][r] + bb;
                    if constexpr (OUT_BF16)
                        Cb[(size_t)m * N + n] = f2bf(v);
                    else
                        ((float*)Cf)[(size_t)m * N + n] = v;
                }
        }
    }
}

// Flash attention: 4 waves, 32 queries/wave, KV tiles of 64.
// v3 (bisect): double-buffered K/V staging + ones-column-MFMA row sums.
// P round-trip kept as the proven row-major [q][k] pad-72 path.
__global__ __launch_bounds__(256) void flash_attn(
    const short* __restrict__ Q, const short* __restrict__ Kb,
    const short* __restrict__ VT, const int* __restrict__ mask,
    short* __restrict__ Ctx)
{
    const int S = 2048, D = 1024;
    __shared__ short Ks[2][64 * 64];
    __shared__ short Vs[2][64 * 64];
    __shared__ short Ps[4][32 * 72];

    const int tid = threadIdx.x;
    const int wave = tid >> 6, lane = tid & 63;
    const int quad = lane >> 4, l16 = lane & 15;
    const int q0 = blockIdx.x * 128 + wave * 32;
    const int head = blockIdx.y, b = blockIdx.z;
    const size_t qbase  = ((size_t)(b * S)) * D + head * 64;
    const size_t vtbase = ((size_t)((b * 16 + head) * 64)) * S;
    const int rowA = lane >> 3;
    const int chunkS = (((lane & 7) ^ rowA) * 8);
    const int rsw = (l16 & 7);

    short8 qf[2][2];
    #pragma unroll
    for (int qi = 0; qi < 2; ++qi)
        #pragma unroll
        for (int h = 0; h < 2; ++h)
            qf[qi][h] = *(const short8*)(Q + qbase + (size_t)(q0 + qi * 16 + l16) * D + h * 32 + quad * 8);

    f32x4 o[2][4] = {};
    f32x4 osum[2] = {};
    const short8 ones = { (short)0x3F80, (short)0x3F80, (short)0x3F80, (short)0x3F80,
                          (short)0x3F80, (short)0x3F80, (short)0x3F80, (short)0x3F80 };

    const int* mrow = mask + (size_t)b * S;
    short* Pw = Ps[wave];
    const int slot0 = (quad ^ rsw) * 8;
    const int slot1 = ((4 + quad) ^ rsw) * 8;

    auto STAGE = [&](int kts, int bufi) {
        const int r0 = wave * 16;
        gl_lds16(Kb + qbase + (size_t)(kts + r0 + rowA) * D + chunkS,      &Ks[bufi][r0 * 64]);
        gl_lds16(Kb + qbase + (size_t)(kts + r0 + 8 + rowA) * D + chunkS,  &Ks[bufi][(r0 + 8) * 64]);
        gl_lds16(VT + vtbase + (size_t)(r0 + rowA) * S + kts + chunkS,     &Vs[bufi][r0 * 64]);
        gl_lds16(VT + vtbase + (size_t)(r0 + 8 + rowA) * S + kts + chunkS, &Vs[bufi][(r0 + 8) * 64]);
    };

    STAGE(0, 0);
    __syncthreads();   // drains vmcnt(0): tile 0 resident

    for (int kt = 0; kt < S; kt += 64) {
        const int cur = (kt >> 6) & 1;
        if (kt + 64 < S) STAGE(kt + 64, cur ^ 1);   // in flight during compute

        const short* Kc = &Ks[cur][0];
        const short* Vc = &Vs[cur][0];

        // S = Q K^T; p = exp2(fma(S, scale*log2e, maskbias))
        float p[2][4][4];
        #pragma unroll
        for (int t = 0; t < 4; ++t) {
            short8 kf0 = *(const short8*)(Kc + (t * 16 + l16) * 64 + slot0);
            short8 kf1 = *(const short8*)(Kc + (t * 16 + l16) * 64 + slot1);
            float mb = mrow[kt + t * 16 + l16] != 0 ? 0.f : -1e30f;
            #pragma unroll
            for (int qi = 0; qi < 2; ++qi) {
                f32x4 a = {};
                a = __builtin_amdgcn_mfma_f32_16x16x32_bf16(qf[qi][0], kf0, a, 0, 0, 0);
                a = __builtin_amdgcn_mfma_f32_16x16x32_bf16(qf[qi][1], kf1, a, 0, 0, 0);
                #pragma unroll
                for (int r = 0; r < 4; ++r)
                    p[qi][t][r] = __builtin_amdgcn_exp2f(__builtin_fmaf(a[r], SCLOG, mb));
            }
        }

        // P: C-layout -> LDS (wave-private, padded) -> A-frag layout
        #pragma unroll
        for (int qi = 0; qi < 2; ++qi)
            #pragma unroll
            for (int t = 0; t < 4; ++t)
                #pragma unroll
                for (int r = 0; r < 4; ++r)
                    Pw[(qi * 16 + quad * 4 + r) * 72 + t * 16 + l16] = f2bf(p[qi][t][r]);

        // O += P V ; row-sums via ones-column MFMA (same C layout as o)
        __builtin_amdgcn_s_setprio(1);
        #pragma unroll
        for (int h = 0; h < 2; ++h) {
            const int vslot = ((h * 4 + quad) ^ rsw) * 8;
            short8 pa0 = *(const short8*)(Pw + l16 * 72 + h * 32 + quad * 8);
            short8 pa1 = *(const short8*)(Pw + (16 + l16) * 72 + h * 32 + quad * 8);
            osum[0] = __builtin_amdgcn_mfma_f32_16x16x32_bf16(pa0, ones, osum[0], 0, 0, 0);
            osum[1] = __builtin_amdgcn_mfma_f32_16x16x32_bf16(pa1, ones, osum[1], 0, 0, 0);
            #pragma unroll
            for (int nt = 0; nt < 4; ++nt) {
                short8 bv = *(const short8*)(Vc + (nt * 16 + l16) * 64 + vslot);
                o[0][nt] = __builtin_amdgcn_mfma_f32_16x16x32_bf16(pa0, bv, o[0][nt], 0, 0, 0);
                o[1][nt] = __builtin_amdgcn_mfma_f32_16x16x32_bf16(pa1, bv, o[1][nt], 0, 0, 0);
            }
        }
        __builtin_amdgcn_s_setprio(0);
        __syncthreads();   // drains prefetch; joins waves before buffer swap
    }

    float inv[2][4];
    #pragma unroll
    for (int qi = 0; qi < 2; ++qi)
        #pragma unroll
        for (int r = 0; r < 4; ++r)
            inv[qi][r] = 1.0f / osum[qi][r];

    #pragma unroll
    for (int qi = 0; qi < 2; ++qi)
        #pragma unroll
        for (int nt = 0; nt < 4; ++nt)
            #pragma unroll
            for (int r = 0; r < 4; ++r) {
                float v = o[qi][nt][r] * inv[qi][r];
                Ctx[qbase + (size_t)(q0 + qi * 16 + quad * 4 + r) * D + nt * 16 + l16] = f2bf(v);
            }
}

extern "C" void kernel_launch(void* const* d_in, const int* in_sizes, int n_in,
                              void* d_out, int out_size, void* d_ws, size_t ws_size,
                              hipStream_t stream) {
    const int B = 4, S = 2048, D = 1024, H = 16;
    const int M = B * S;                 // 8192
    const size_t MD = (size_t)M * D;

    const float* q_in = (const float*)d_in[0];
    const float* k_in = (const float*)d_in[1];
    const float* v_in = (const float*)d_in[2];
    const int* mask = (const int*)d_in[3];
    const float* Wq = (const float*)d_in[4];
    const float* bq = (const float*)d_in[5];
    const float* Wk = (const float*)d_in[6];
    const float* bk = (const float*)d_in[7];
    const float* Wv = (const float*)d_in[8];
    const float* bv = (const float*)d_in[9];
    const float* Wo = (const float*)d_in[10];
    const float* bo = (const float*)d_in[11];

    // ws slots (16.78 MB each):
    //  S1: qbf   S2: kbf -> Ctx   S3: vbf   S4: Qb   S5: Kb2   S6: VT
    short* S1 = (short*)d_ws;
    short* S2 = S1 + MD;
    short* S3 = S2 + MD;
    short* S4 = S3 + MD;
    short* wqb = S4 + MD;
    short* wkb = wqb + (size_t)D * D;
    short* wvb = wkb + (size_t)D * D;
    short* wob = wvb + (size_t)D * D;
    short* S5 = wob + (size_t)D * D;
    short* S6 = S5 + MD;

    short *qbf = S1, *kbf = S2, *vbf = S3;
    short *Qb = S4, *Kb2 = S5, *VTb = S6, *Ctx = S2;

    dim3 blk(256);
    int n8_in = (int)(MD / 8);
    int n8_w  = D * D / 8;
    cvt3<<<dim3((n8_in + 255) / 256, 3), blk, 0, stream>>>(
        q_in, k_in, v_in, qbf, kbf, vbf, n8_in);
    cvt4<<<dim3((n8_w + 255) / 256, 4), blk, 0, stream>>>(
        Wq, Wk, Wv, Wo, wqb, wkb, wvb, wob, n8_w);

    // fused QKV projection; z==2 writes V transposed directly into VT
    // (z=0: A=qbf->Qb(S4); z=1: A=kbf->Kb2(S5); z=2: A=vbf->VT(S6) — no alias)
    dim3 g1(D / 128, M / 128, 3);
    gemm_bt_bf16<3, true, true><<<g1, blk, 0, stream>>>(
        qbf, kbf, vbf, wqb, wkb, wvb, bq, bk, bv,
        Qb, Kb2, VTb, nullptr, M, D, D);

    dim3 g2(S / 128, H, B);
    flash_attn<<<g2, blk, 0, stream>>>(Qb, Kb2, VTb, mask, Ctx);

    dim3 g3(D / 128, M / 128, 1);
    gemm_bt_bf16<1, false, false><<<g3, blk, 0, stream>>>(
        Ctx, nullptr, nullptr, wob, nullptr, nullptr, bo, nullptr, nullptr,
        nullptr, nullptr, nullptr, (float*)d_out, M, D, D);
}